// Round 1
// baseline (484.067 us; speedup 1.0000x reference)
//
#include <hip/hip_runtime.h>
#include <hip/hip_bf16.h>
#include <math.h>

#define B_ 8
#define N_ 2048
#define F_ 128

// ---------------------------------------------------------------------------
// Kernel 1: Wh = h @ W^T  (16384x128x128), fused s = Wh@a_src, t = Wh@a_dst
// grid 512 x 256 threads; each block: 32 rows.
// ---------------------------------------------------------------------------
__global__ __launch_bounds__(256) void k_wh(
    const float* __restrict__ h, const float* __restrict__ W,
    const float* __restrict__ a,
    float* __restrict__ Wh, float* __restrict__ sv, float* __restrict__ tv)
{
    __shared__ float Wt[F_][F_ + 1];   // transposed W, padded: reads conflict-free
    __shared__ float hrow[8][F_];
    __shared__ float sred[4][4], tred[4][4];

    const int tid  = threadIdx.x;
    const int o    = tid & 127;
    const int half = tid >> 7;
    const int wid  = tid >> 6;
    const int lane = tid & 63;

    for (int idx = tid; idx < F_ * F_; idx += 256) {
        int oo = idx >> 7, ff = idx & 127;
        Wt[ff][oo] = W[idx];
    }
    const float a_s = a[o];
    const float a_d = a[F_ + o];
    __syncthreads();

    const int row0 = blockIdx.x * 32;
    for (int it = 0; it < 4; ++it) {
        const int rbase = row0 + it * 8;
        for (int idx = tid; idx < 8 * F_; idx += 256)
            hrow[idx >> 7][idx & 127] =
                h[(size_t)(rbase + (idx >> 7)) * F_ + (idx & 127)];
        __syncthreads();

        const int hr = half * 4;
        float acc0 = 0.f, acc1 = 0.f, acc2 = 0.f, acc3 = 0.f;
        for (int f = 0; f < F_; f += 4) {
            float w0 = Wt[f + 0][o], w1 = Wt[f + 1][o];
            float w2 = Wt[f + 2][o], w3 = Wt[f + 3][o];
            float4 h0 = *(const float4*)&hrow[hr + 0][f];
            float4 h1 = *(const float4*)&hrow[hr + 1][f];
            float4 h2 = *(const float4*)&hrow[hr + 2][f];
            float4 h3 = *(const float4*)&hrow[hr + 3][f];
            acc0 += h0.x * w0 + h0.y * w1 + h0.z * w2 + h0.w * w3;
            acc1 += h1.x * w0 + h1.y * w1 + h1.z * w2 + h1.w * w3;
            acc2 += h2.x * w0 + h2.y * w1 + h2.z * w2 + h2.w * w3;
            acc3 += h3.x * w0 + h3.y * w1 + h3.z * w2 + h3.w * w3;
        }
        const int r = rbase + hr;
        Wh[(size_t)(r + 0) * F_ + o] = acc0;
        Wh[(size_t)(r + 1) * F_ + o] = acc1;
        Wh[(size_t)(r + 2) * F_ + o] = acc2;
        Wh[(size_t)(r + 3) * F_ + o] = acc3;

        float accs[4] = {acc0, acc1, acc2, acc3};
        #pragma unroll
        for (int q = 0; q < 4; ++q) {
            float vs = accs[q] * a_s;
            float vt = accs[q] * a_d;
            #pragma unroll
            for (int k = 32; k; k >>= 1) {
                vs += __shfl_xor(vs, k, 64);
                vt += __shfl_xor(vt, k, 64);
            }
            if (lane == 0) { sred[wid][q] = vs; tred[wid][q] = vt; }
        }
        __syncthreads();
        if (tid < 8) {
            int g = tid >> 2, q = tid & 3;
            int rr = rbase + g * 4 + q;
            sv[rr] = sred[g * 2][q] + sred[g * 2 + 1][q];
            tv[rr] = tred[g * 2][q] + tred[g * 2 + 1][q];
        }
        __syncthreads();
    }
}

// ---------------------------------------------------------------------------
// Kernel 2: masked softmax over j + out = alpha @ Wh.
// One block per (b, 8-row i-tile): 2048 blocks x 256 threads (8 blocks/CU).
// Phase A: online (m,l) per row, 32 lanes/row, single adj pass.
// Phase B: 256-j chunks; weights staged in LDS [jc][8]; inner loop:
//          1 coalesced Wh load + 2 broadcast ds_read_b128 + 8 FMA.
// ---------------------------------------------------------------------------
__global__ __launch_bounds__(256) void k_attn(
    const float* __restrict__ Wh, const float* __restrict__ sv,
    const float* __restrict__ tv, const int* __restrict__ adj,
    float* __restrict__ out)
{
    __shared__ float wsm[256][8];   // weights chunk: [jc][row]
    __shared__ float red[128][8];   // half-combine
    __shared__ float mrow[8], lrow[8], srow[8], ilrow[8];

    const int tid = threadIdx.x;
    const int b  = blockIdx.x >> 8;
    const int i0 = (blockIdx.x & 255) * 8;
    const float* tb = tv + b * N_;

    // ---- Phase A: online softmax stats ----
    {
        const int r = tid >> 5, lane = tid & 31;
        const float si = sv[b * N_ + i0 + r];
        const int* adjrow = adj + (size_t)(b * N_ + i0 + r) * N_;
        float m = -INFINITY, l = 0.f;
        for (int j = lane; j < N_; j += 32) {
            if (adjrow[j] != 0) {
                float e = si + tb[j];
                e = e > 0.f ? e : 0.2f * e;
                float mn = fmaxf(m, e);
                l = l * __expf(m - mn) + __expf(e - mn);
                m = mn;
            }
        }
        #pragma unroll
        for (int k = 16; k; k >>= 1) {
            float mo = __shfl_xor(m, k, 32);
            float lo = __shfl_xor(l, k, 32);
            float mn = fmaxf(m, mo);
            float ln = (l  == 0.f ? 0.f : l  * __expf(m  - mn))
                     + (lo == 0.f ? 0.f : lo * __expf(mo - mn));
            m = mn; l = ln;
        }
        if (lane == 0) {
            mrow[r] = m; lrow[r] = l; srow[r] = si;
            ilrow[r] = (l > 0.f) ? 1.f / l : 0.f;   // l==0 row -> output 0 (nan_to_num)
        }
    }
    __syncthreads();

    float sreg[8], mreg[8];
    #pragma unroll
    for (int q = 0; q < 8; ++q) { sreg[q] = srow[q]; mreg[q] = mrow[q]; }

    const int o    = tid & 127;
    const int half = tid >> 7;
    const float* Whb = Wh + (size_t)b * N_ * F_;
    float acc[8] = {0.f, 0.f, 0.f, 0.f, 0.f, 0.f, 0.f, 0.f};

    for (int j0 = 0; j0 < N_; j0 += 256) {
        // stage weights for this chunk
        {
            const int j = j0 + tid;
            const float tj = tb[j];
            const int* ap = adj + (size_t)(b * N_ + i0) * N_ + j;
            #pragma unroll
            for (int q = 0; q < 8; ++q) {
                int a_ = ap[(size_t)q * N_];
                float e = sreg[q] + tj;
                e = e > 0.f ? e : 0.2f * e;
                wsm[tid][q] = a_ ? __expf(e - mreg[q]) : 0.f;
            }
        }
        __syncthreads();

        const float* whp = Whb + (size_t)(j0 + half * 128) * F_ + o;
        const float* wp  = &wsm[half * 128][0];
        #pragma unroll 4
        for (int jj = 0; jj < 128; ++jj) {
            float wh = whp[(size_t)jj * F_];
            float4 w0 = *(const float4*)(wp + jj * 8);
            float4 w1 = *(const float4*)(wp + jj * 8 + 4);
            acc[0] += w0.x * wh; acc[1] += w0.y * wh;
            acc[2] += w0.z * wh; acc[3] += w0.w * wh;
            acc[4] += w1.x * wh; acc[5] += w1.y * wh;
            acc[6] += w1.z * wh; acc[7] += w1.w * wh;
        }
        __syncthreads();
    }

    if (half == 1) {
        #pragma unroll
        for (int q = 0; q < 8; ++q) red[o][q] = acc[q];
    }
    __syncthreads();
    if (half == 0) {
        #pragma unroll
        for (int q = 0; q < 8; ++q) {
            float v = (acc[q] + red[o][q]) * ilrow[q];
            out[(size_t)(b * N_ + i0 + q) * F_ + o] = v;
        }
    }
}

extern "C" void kernel_launch(void* const* d_in, const int* in_sizes, int n_in,
                              void* d_out, int out_size, void* d_ws, size_t ws_size,
                              hipStream_t stream) {
    const float* h   = (const float*)d_in[0];
    const int*   adj = (const int*)d_in[1];
    const float* W   = (const float*)d_in[2];
    const float* a   = (const float*)d_in[3];
    float* out = (float*)d_out;

    float* Wh = (float*)d_ws;                 // 16384*128 floats = 8 MB
    float* sv = Wh + (size_t)B_ * N_ * F_;    // 16384 floats
    float* tv = sv + (size_t)B_ * N_;         // 16384 floats

    k_wh<<<512, 256, 0, stream>>>(h, W, a, Wh, sv, tv);
    k_attn<<<2048, 256, 0, stream>>>(Wh, sv, tv, adj, out);
}

// Round 2
// 241.044 us; speedup vs baseline: 2.0082x; 2.0082x over previous
//
#include <hip/hip_runtime.h>
#include <hip/hip_bf16.h>
#include <hip/hip_fp16.h>
#include <math.h>

#define B_ 8
#define N_ 2048
#define F_ 128

typedef __attribute__((ext_vector_type(8))) _Float16 half8;
typedef __attribute__((ext_vector_type(4))) float f32x4;

// ---------------------------------------------------------------------------
// Kernel 1: Wh = h @ W^T (fp32 compute), output:
//   - WhH: fp16, swizzled into MFMA B-fragment order:
//       element (b, j, o) at ((b*64 + j/32)*128 + o)*32 + ((j/8)%4)*8 + (j%8)
//   - sv = h . (W^T a_src), tv = h . (W^T a_dst)  (exact fp32)
// grid 512 = 256 row-blocks x 2 o-halves; 256 threads; 64 rows x 64 o per blk
// ---------------------------------------------------------------------------
__global__ __launch_bounds__(256) void k_wh(
    const float* __restrict__ h, const float* __restrict__ W,
    const float* __restrict__ a,
    _Float16* __restrict__ WhH, float* __restrict__ sv, float* __restrict__ tv)
{
    __shared__ float h_s[64][129];   // stride 129: main-loop reads 2-way (free)
    __shared__ float Wt[128][68];    // [k][o'], stride 68 keeps b128 aligned
    __shared__ float wsm[128], wtm[128];
    __shared__ float sred[64][4], tred[64][4];

    const int t = threadIdx.x;
    const int rowblk = blockIdx.x >> 1;
    const int ohalf  = blockIdx.x & 1;
    const int r0 = rowblk * 64;

    // stage h (coalesced float4 reads, scalar LDS writes)
    {
        const int f = (t & 31) * 4;
        #pragma unroll
        for (int it = 0; it < 8; ++it) {
            const int r = (t >> 5) + it * 8;
            float4 v = *(const float4*)&h[(size_t)(r0 + r) * F_ + f];
            h_s[r][f] = v.x; h_s[r][f + 1] = v.y;
            h_s[r][f + 2] = v.z; h_s[r][f + 3] = v.w;
        }
    }
    // stage W transposed (this o-half): Wt[k][o']
    {
        const int f = (t & 31) * 4;
        #pragma unroll
        for (int it = 0; it < 8; ++it) {
            const int o = (t >> 5) + it * 8;
            float4 v = *(const float4*)&W[(size_t)(ohalf * 64 + o) * F_ + f];
            Wt[f][o] = v.x; Wt[f + 1][o] = v.y;
            Wt[f + 2][o] = v.z; Wt[f + 3][o] = v.w;
        }
    }
    // ws[f] = sum_o W[o][f]*a[o]; wt[f] = sum_o W[o][f]*a[128+o]
    {
        const int f = t & 127;
        const int which = t >> 7;
        const float* av = a + which * 128;
        float acc = 0.f;
        for (int o = 0; o < 128; ++o)
            acc += W[(size_t)o * F_ + f] * av[o];
        if (which == 0) wsm[f] = acc; else wtm[f] = acc;
    }
    __syncthreads();

    // main GEMM: thread (o4 = t&15, r4 = t>>4) computes 4x4 microtile
    const int o4 = t & 15;
    const int r4 = t >> 4;
    float acc[4][4];
    #pragma unroll
    for (int i = 0; i < 4; ++i)
        #pragma unroll
        for (int j = 0; j < 4; ++j) acc[i][j] = 0.f;

    #pragma unroll 4
    for (int k = 0; k < 128; ++k) {
        float4 w = *(const float4*)&Wt[k][o4 * 4];
        float h0 = h_s[r4 * 4 + 0][k];
        float h1 = h_s[r4 * 4 + 1][k];
        float h2 = h_s[r4 * 4 + 2][k];
        float h3 = h_s[r4 * 4 + 3][k];
        acc[0][0] += h0 * w.x; acc[0][1] += h0 * w.y; acc[0][2] += h0 * w.z; acc[0][3] += h0 * w.w;
        acc[1][0] += h1 * w.x; acc[1][1] += h1 * w.y; acc[1][2] += h1 * w.z; acc[1][3] += h1 * w.w;
        acc[2][0] += h2 * w.x; acc[2][1] += h2 * w.y; acc[2][2] += h2 * w.z; acc[2][3] += h2 * w.w;
        acc[3][0] += h3 * w.x; acc[3][1] += h3 * w.y; acc[3][2] += h3 * w.z; acc[3][3] += h3 * w.w;
    }

    // store WhH in B-fragment swizzled fp16 layout
    {
        const int Rbase = r0 + r4 * 4;         // 4 consecutive rows (same k8)
        const int b    = Rbase >> 11;
        const int jj   = Rbase & 2047;
        const int jblk = jj >> 5;
        const int k8   = (jj >> 3) & 3;
        const int kk   = jj & 7;               // 0 or 4
        #pragma unroll
        for (int jo = 0; jo < 4; ++jo) {
            const int o = ohalf * 64 + o4 * 4 + jo;
            size_t off = ((size_t)(b * 64 + jblk) * 128 + o) * 32 + k8 * 8 + kk;
            union { _Float16 x[4]; uint2 u; } pk;
            pk.x[0] = (_Float16)acc[0][jo];
            pk.x[1] = (_Float16)acc[1][jo];
            pk.x[2] = (_Float16)acc[2][jo];
            pk.x[3] = (_Float16)acc[3][jo];
            *(uint2*)(WhH + off) = pk.u;       // 8B aligned (kk in {0,4})
        }
    }

    // s, t (fp32 exact): 4 partials per row
    {
        const int r = t & 63, part = t >> 6;
        float as_ = 0.f, at_ = 0.f;
        const int kb = part * 32;
        for (int k = kb; k < kb + 32; ++k) {
            float hv = h_s[r][k];
            as_ += hv * wsm[k];
            at_ += hv * wtm[k];
        }
        sred[r][part] = as_; tred[r][part] = at_;
    }
    __syncthreads();
    if (ohalf == 0 && t < 64) {
        sv[r0 + t] = sred[t][0] + sred[t][1] + sred[t][2] + sred[t][3];
        tv[r0 + t] = tred[t][0] + tred[t][1] + tred[t][2] + tred[t][3];
    }
}

// ---------------------------------------------------------------------------
// Kernel 2: flash-GAT. One block per (b, 16-row i-tile): 1024 blocks x 256.
// P = adj ? exp(leaky(s_i + t_j) - M_i) : 0,  M_i = max(s_i + tmax_b, 0) >= e.
// PV via mfma_f32_16x16x32_f16; P through LDS in A-frag order (double-buffer);
// Wh B-frags loaded directly from swizzled global (16B/lane coalesced).
// ---------------------------------------------------------------------------
__global__ __launch_bounds__(256) void k_attn(
    const _Float16* __restrict__ WhH, const float* __restrict__ sv,
    const float* __restrict__ tv, const int* __restrict__ adj,
    float* __restrict__ out)
{
    __shared__ _Float16 Pl[2][16][40];   // stride 40 halves = 80B (16B-mult)
    __shared__ float il[16];
    __shared__ float tmr[4];

    const int t  = threadIdx.x;
    const int b  = blockIdx.x >> 7;
    const int i0 = (blockIdx.x & 127) * 16;
    const float* tb = tv + ((size_t)b << 11);

    // per-batch tmax (L2-hot 8KB read + reduce)
    float tm = -INFINITY;
    #pragma unroll
    for (int k = 0; k < 8; ++k) tm = fmaxf(tm, tb[t + k * 256]);
    #pragma unroll
    for (int k = 32; k; k >>= 1) tm = fmaxf(tm, __shfl_xor(tm, k, 64));
    if ((t & 63) == 0) tmr[t >> 6] = tm;
    __syncthreads();
    const float tmax = fmaxf(fmaxf(tmr[0], tmr[1]), fmaxf(tmr[2], tmr[3]));

    const int i_a = t >> 5;   // 0..7 -> rows i_a and i_a+8
    const int jl  = t & 31;
    const float s0 = sv[((size_t)b << 11) + i0 + i_a];
    const float s1 = sv[((size_t)b << 11) + i0 + i_a + 8];
    const float M0 = fmaxf(s0 + tmax, 0.f);
    const float M1 = fmaxf(s1 + tmax, 0.f);

    const int* arow0 = adj + ((size_t)(((size_t)b << 11) + i0 + i_a) << 11);
    const int* arow1 = arow0 + ((size_t)8 << 11);

    const int lane = t & 63;
    const int wv   = t >> 6;
    const int m_   = lane & 15;
    const int q_   = lane >> 4;

    f32x4 accA = {0.f, 0.f, 0.f, 0.f};
    f32x4 accB = {0.f, 0.f, 0.f, 0.f};
    float lsum0 = 0.f, lsum1 = 0.f;

    int   a0 = arow0[jl], a1 = arow1[jl];
    float tj = tb[jl];

    for (int jc = 0; jc < 64; ++jc) {
        // software-prefetch next chunk's adj/t (wraps at the end: harmless)
        const int jn = ((jc + 1) & 63) * 32;
        const int   na0 = arow0[jn + jl];
        const int   na1 = arow1[jn + jl];
        const float ntj = tb[jn + jl];

        // B fragments for this chunk (coalesced 16B/lane from L2)
        const _Float16* wb = WhH + ((size_t)(b * 64 + jc) << 12) + q_ * 8;
        half8 bf0 = *(const half8*)(wb + (size_t)(wv * 32 + m_) * 32);
        half8 bf1 = *(const half8*)(wb + (size_t)(wv * 32 + 16 + m_) * 32);

        // P values
        float e0 = s0 + tj; e0 = fmaxf(e0, 0.2f * e0);
        float p0 = a0 ? __expf(e0 - M0) : 0.f;
        float e1 = s1 + tj; e1 = fmaxf(e1, 0.2f * e1);
        float p1 = a1 ? __expf(e1 - M1) : 0.f;
        lsum0 += p0; lsum1 += p1;

        const int bufc = jc & 1;
        Pl[bufc][i_a][jl]     = (_Float16)p0;
        Pl[bufc][i_a + 8][jl] = (_Float16)p1;
        __syncthreads();

        half8 af = *(const half8*)&Pl[bufc][m_][q_ * 8];
        accA = __builtin_amdgcn_mfma_f32_16x16x32_f16(af, bf0, accA, 0, 0, 0);
        accB = __builtin_amdgcn_mfma_f32_16x16x32_f16(af, bf1, accB, 0, 0, 0);

        a0 = na0; a1 = na1; tj = ntj;
    }

    // row sums -> 1/l  (reduce over the 32 j-lanes of each half-wave)
    #pragma unroll
    for (int k = 16; k; k >>= 1) {
        lsum0 += __shfl_xor(lsum0, k, 64);
        lsum1 += __shfl_xor(lsum1, k, 64);
    }
    if (jl == 0) {
        il[i_a]     = lsum0 > 0.f ? 1.f / lsum0 : 0.f;
        il[i_a + 8] = lsum1 > 0.f ? 1.f / lsum1 : 0.f;
    }
    __syncthreads();

    // epilogue: C/D layout col=lane&15, row=(lane>>4)*4+reg
    float* outb = out + (((size_t)((b << 11) + i0)) << 7);
    #pragma unroll
    for (int reg = 0; reg < 4; ++reg) {
        const int row = q_ * 4 + reg;
        const float sc = il[row];
        outb[(size_t)row * 128 + wv * 32 + m_]      = accA[reg] * sc;
        outb[(size_t)row * 128 + wv * 32 + 16 + m_] = accB[reg] * sc;
    }
}

extern "C" void kernel_launch(void* const* d_in, const int* in_sizes, int n_in,
                              void* d_out, int out_size, void* d_ws, size_t ws_size,
                              hipStream_t stream) {
    const float* h   = (const float*)d_in[0];
    const int*   adj = (const int*)d_in[1];
    const float* W   = (const float*)d_in[2];
    const float* a   = (const float*)d_in[3];
    float* out = (float*)d_out;

    _Float16* WhH = (_Float16*)d_ws;                         // 4 MB
    float* sv = (float*)((char*)d_ws + (size_t)4 * 1024 * 1024);
    float* tv = sv + (size_t)B_ * N_;

    k_wh<<<512, 256, 0, stream>>>(h, W, a, WhH, sv, tv);
    k_attn<<<1024, 256, 0, stream>>>(WhH, sv, tv, adj, out);
}